// Round 1
// baseline (1391.609 us; speedup 1.0000x reference)
//
#include <hip/hip_runtime.h>

#define H_DIM 128
#define F_IN  384

typedef __bf16 v8bf __attribute__((ext_vector_type(8)));
typedef float  v4f  __attribute__((ext_vector_type(4)));

// order-preserving float <-> uint encoding for atomicMax
__device__ __forceinline__ unsigned enc_f32(float v) {
    unsigned u = __float_as_uint(v);
    return (u & 0x80000000u) ? ~u : (u | 0x80000000u);
}
__device__ __forceinline__ float dec_f32(unsigned e) {
    if (e == 0u) return 0.0f;  // untouched node -> 0 (matches reference where())
    unsigned u = (e & 0x80000000u) ? (e & 0x7fffffffu) : ~e;
    return __uint_as_float(u);
}

// W1 [F_IN][H] fp32 -> W1T [H][F_IN] bf16 ; W2 [H][H] fp32 -> W2T [H][H] bf16
__global__ __launch_bounds__(256) void wconvert(const float* __restrict__ W1,
                                                const float* __restrict__ W2,
                                                __bf16* __restrict__ W1T,
                                                __bf16* __restrict__ W2T) {
    int i = blockIdx.x * 256 + threadIdx.x;
    if (i < F_IN * H_DIM) {
        int col = i / F_IN, k = i % F_IN;
        W1T[i] = (__bf16)W1[k * H_DIM + col];
    } else if (i < F_IN * H_DIM + H_DIM * H_DIM) {
        int j = i - F_IN * H_DIM;
        int col = j / H_DIM, k = j % H_DIM;
        W2T[j] = (__bf16)W2[k * H_DIM + col];
    }
}

// 128 edges per block, 256 threads (4 waves). Wave w owns edges w*32..w*32+31
// as two 16-row A-groups (A/B); every W1/W2 B-fragment is loaded once and fed
// to two MFMAs (register reuse) -> halves LDS/L2 B-operand traffic per edge.
__global__ __launch_bounds__(256) void mlp_scatter(
    const float* __restrict__ leaf, const int* __restrict__ nidx,
    const __bf16* __restrict__ W1T, const __bf16* __restrict__ W2T,
    const float* __restrict__ b1, const float* __restrict__ b2,
    unsigned* __restrict__ agg, int E)
{
    __shared__ __bf16 wb[2][128][40];   // W1T k-chunk double buffer (pad 40 -> 2-way max)
    __shared__ __bf16 hs[128][136];     // relu hidden, bf16 (pad 136 -> 2-way max)
    __shared__ int   idx_s[128];
    __shared__ float b1_s[H_DIM], b2_s[H_DIM];

    const int t  = threadIdx.x;
    const int w  = t >> 6;
    const int l  = t & 63;
    const int lr = l & 15;   // row/col within fragment
    const int lg = l >> 4;   // k-group
    const long e0 = (long)blockIdx.x * 128;

    if (t < 128) {
        long e = e0 + t;
        idx_s[t] = nidx[e < E ? e : (E - 1)];
    }
    if (t < H_DIM) { b1_s[t] = b1[t]; b2_s[t] = b2[t]; }

    // stage W1T chunk ks=0 into buffer 0 (each thread: 32B of one column)
    {
        const int col = t >> 1, kh = (t & 1) * 16;
        const v8bf* src = (const v8bf*)(W1T + col * F_IN + kh);
        *(v8bf*)&wb[0][col][kh]     = src[0];
        *(v8bf*)&wb[0][col][kh + 8] = src[1];
    }

    long erA = e0 + w * 32 + lr;        // group A rows
    long erB = e0 + w * 32 + 16 + lr;   // group B rows
    if (erA >= E) erA = E - 1;          // clamp (tail-safe)
    if (erB >= E) erB = E - 1;
    const float* arowA = leaf + erA * (long)F_IN + lg * 8;
    const float* arowB = leaf + erB * (long)F_IN + lg * 8;

    const v4f vzero = {0.f, 0.f, 0.f, 0.f};
    v4f accA[8], accB[8];
#pragma unroll
    for (int f = 0; f < 8; ++f) { accA[f] = vzero; accB[f] = vzero; }

    float4 aA0 = *(const float4*)(arowA);
    float4 aA1 = *(const float4*)(arowA + 4);
    float4 aB0 = *(const float4*)(arowB);
    float4 aB1 = *(const float4*)(arowB + 4);
    __syncthreads();

    // ---- layer 1: h = x @ W1, K=384 in 12 steps of 32 ----
    for (int ks = 0; ks < 12; ++ks) {
        float4 nA0 = aA0, nA1 = aA1, nB0 = aB0, nB1 = aB1;
        if (ks + 1 < 12) {
            nA0 = *(const float4*)(arowA + (ks + 1) * 32);
            nA1 = *(const float4*)(arowA + (ks + 1) * 32 + 4);
            nB0 = *(const float4*)(arowB + (ks + 1) * 32);
            nB1 = *(const float4*)(arowB + (ks + 1) * 32 + 4);
            const int col = t >> 1, kh = (t & 1) * 16;
            const v8bf* src = (const v8bf*)(W1T + col * F_IN + (ks + 1) * 32 + kh);
            const int b = (ks + 1) & 1;
            *(v8bf*)&wb[b][col][kh]     = src[0];
            *(v8bf*)&wb[b][col][kh + 8] = src[1];
        }
        v8bf afA, afB;
        afA[0] = (__bf16)aA0.x; afA[1] = (__bf16)aA0.y; afA[2] = (__bf16)aA0.z; afA[3] = (__bf16)aA0.w;
        afA[4] = (__bf16)aA1.x; afA[5] = (__bf16)aA1.y; afA[6] = (__bf16)aA1.z; afA[7] = (__bf16)aA1.w;
        afB[0] = (__bf16)aB0.x; afB[1] = (__bf16)aB0.y; afB[2] = (__bf16)aB0.z; afB[3] = (__bf16)aB0.w;
        afB[4] = (__bf16)aB1.x; afB[5] = (__bf16)aB1.y; afB[6] = (__bf16)aB1.z; afB[7] = (__bf16)aB1.w;
        const int cb = ks & 1;
#pragma unroll
        for (int f = 0; f < 8; ++f) {
            v8bf bfv = *(const v8bf*)&wb[cb][f * 16 + lr][lg * 8];
            accA[f] = __builtin_amdgcn_mfma_f32_16x16x32_bf16(afA, bfv, accA[f], 0, 0, 0);
            accB[f] = __builtin_amdgcn_mfma_f32_16x16x32_bf16(afB, bfv, accB[f], 0, 0, 0);
        }
        aA0 = nA0; aA1 = nA1; aB0 = nB0; aB1 = nB1;
        __syncthreads();
    }

    // ---- relu + bias -> bf16 hidden in LDS ----
#pragma unroll
    for (int f = 0; f < 8; ++f) {
        const float bb = b1_s[f * 16 + lr];
#pragma unroll
        for (int j = 0; j < 4; ++j) {
            float vA = fmaxf(accA[f][j] + bb, 0.0f);
            float vB = fmaxf(accB[f][j] + bb, 0.0f);
            hs[w * 32 + lg * 4 + j][f * 16 + lr]      = (__bf16)vA;
            hs[w * 32 + 16 + lg * 4 + j][f * 16 + lr] = (__bf16)vB;
        }
    }
    __syncthreads();

    // ---- layer 2: m = h @ W2, K=128 in 4 steps; W2T frags from L2, reused x2 ----
    v4f acc2A[8], acc2B[8];
#pragma unroll
    for (int f = 0; f < 8; ++f) { acc2A[f] = vzero; acc2B[f] = vzero; }
#pragma unroll
    for (int ks = 0; ks < 4; ++ks) {
        v8bf afA2 = *(const v8bf*)&hs[w * 32 + lr][ks * 32 + lg * 8];
        v8bf afB2 = *(const v8bf*)&hs[w * 32 + 16 + lr][ks * 32 + lg * 8];
#pragma unroll
        for (int f = 0; f < 8; ++f) {
            v8bf bfv = *(const v8bf*)(W2T + (f * 16 + lr) * H_DIM + ks * 32 + lg * 8);
            acc2A[f] = __builtin_amdgcn_mfma_f32_16x16x32_bf16(afA2, bfv, acc2A[f], 0, 0, 0);
            acc2B[f] = __builtin_amdgcn_mfma_f32_16x16x32_bf16(afB2, bfv, acc2B[f], 0, 0, 0);
        }
    }

    // ---- epilogue: + b2, encode, read-filtered scatter-max ----
    // With ~15 edges/node, most candidates lose to the current running max;
    // a plain read (L2/L3-hit, agg is 32MB) gates ~4-5x of the atomics away.
#pragma unroll
    for (int g = 0; g < 2; ++g) {
        const int rb = w * 32 + g * 16 + lg * 4;
#pragma unroll
        for (int j = 0; j < 4; ++j) {
            const long ej = e0 + rb + j;
            if (ej < E) {
                const int node = idx_s[rb + j];
                unsigned* dst = agg + (long)node * H_DIM + lr;
#pragma unroll
                for (int f = 0; f < 8; ++f) {
                    float v = (g ? acc2B[f][j] : acc2A[f][j]) + b2_s[f * 16 + lr];
                    unsigned en = enc_f32(v);
                    if (en > dst[f * 16]) atomicMax(dst + f * 16, en);
                }
            }
        }
    }
}

// one wave per node row: lang = center + dec(agg); out = cos(gcn, lang)
__global__ __launch_bounds__(256) void cos_kernel(
    const float* __restrict__ center, const float* __restrict__ gcn,
    const unsigned* __restrict__ agg, float* __restrict__ out, int N)
{
    const int w = threadIdx.x >> 6, l = threadIdx.x & 63;
    const long row = (long)blockIdx.x * 4 + w;
    if (row >= N) return;
    const float2 g2 = *(const float2*)(gcn    + row * H_DIM + l * 2);
    const float2 c2 = *(const float2*)(center + row * H_DIM + l * 2);
    const uint2  e2 = *(const uint2*) (agg    + row * H_DIM + l * 2);
    const float l0 = c2.x + dec_f32(e2.x);
    const float l1 = c2.y + dec_f32(e2.y);
    float sgl = g2.x * l0 + g2.y * l1;
    float sgg = g2.x * g2.x + g2.y * g2.y;
    float sll = l0 * l0 + l1 * l1;
#pragma unroll
    for (int off = 32; off; off >>= 1) {
        sgl += __shfl_xor(sgl, off);
        sgg += __shfl_xor(sgg, off);
        sll += __shfl_xor(sll, off);
    }
    if (l == 0) {
        const float na = fmaxf(sqrtf(sgg), 1e-8f);
        const float nb = fmaxf(sqrtf(sll), 1e-8f);
        out[row] = sgl / (na * nb);
    }
}

extern "C" void kernel_launch(void* const* d_in, const int* in_sizes, int n_in,
                              void* d_out, int out_size, void* d_ws, size_t ws_size,
                              hipStream_t stream) {
    const float* center = (const float*)d_in[0];
    const float* leaf   = (const float*)d_in[1];
    const int*   nidx   = (const int*)  d_in[2];
    const float* gcn    = (const float*)d_in[3];
    const float* W1     = (const float*)d_in[4];
    const float* b1     = (const float*)d_in[5];
    const float* W2     = (const float*)d_in[6];
    const float* b2     = (const float*)d_in[7];

    const int E = in_sizes[2];             // 1,000,000
    const int N = in_sizes[0] / H_DIM;     // 65,536

    unsigned* agg = (unsigned*)d_ws;
    const size_t aggBytes = (size_t)N * H_DIM * sizeof(unsigned);
    __bf16* W1T = (__bf16*)((char*)d_ws + aggBytes);
    __bf16* W2T = W1T + (size_t)F_IN * H_DIM;

    hipMemsetAsync(agg, 0, aggBytes, stream);
    wconvert<<<(F_IN * H_DIM + H_DIM * H_DIM + 255) / 256, 256, 0, stream>>>(W1, W2, W1T, W2T);
    mlp_scatter<<<(E + 127) / 128, 256, 0, stream>>>(leaf, nidx, W1T, W2T, b1, b2, agg, E);
    cos_kernel<<<(N + 3) / 4, 256, 0, stream>>>(center, gcn, agg, (float*)d_out, N);
}

// Round 3
// 1313.024 us; speedup vs baseline: 1.0599x; 1.0599x over previous
//
#include <hip/hip_runtime.h>

#define H_DIM 128
#define F_IN  384

typedef __bf16 v8bf __attribute__((ext_vector_type(8)));
typedef float  v4f  __attribute__((ext_vector_type(4)));

// order-preserving float <-> uint encoding for atomicMax
__device__ __forceinline__ unsigned enc_f32(float v) {
    unsigned u = __float_as_uint(v);
    return (u & 0x80000000u) ? ~u : (u | 0x80000000u);
}
__device__ __forceinline__ float dec_f32(unsigned e) {
    if (e == 0u) return 0.0f;  // untouched node -> 0 (matches reference where())
    unsigned u = (e & 0x80000000u) ? (e & 0x7fffffffu) : ~e;
    return __uint_as_float(u);
}

// W1 [F_IN][H] fp32 -> W1T [H][F_IN] bf16 ; W2 [H][H] fp32 -> W2T [H][H] bf16
__global__ __launch_bounds__(256) void wconvert(const float* __restrict__ W1,
                                                const float* __restrict__ W2,
                                                __bf16* __restrict__ W1T,
                                                __bf16* __restrict__ W2T) {
    int i = blockIdx.x * 256 + threadIdx.x;
    if (i < F_IN * H_DIM) {
        int col = i / F_IN, k = i % F_IN;
        W1T[i] = (__bf16)W1[k * H_DIM + col];
    } else if (i < F_IN * H_DIM + H_DIM * H_DIM) {
        int j = i - F_IN * H_DIM;
        int col = j / H_DIM, k = j % H_DIM;
        W2T[j] = (__bf16)W2[k * H_DIM + col];
    }
}

// 64 edges per block, 256 threads (4 waves). Wave w: edges 16w..16w+15, all 128 cols.
// W1T/W2T B-fragments are read directly from global (L2-resident: 96KB/32KB) --
// no LDS weight staging, no double-buffer barriers. Only 2 __syncthreads per block.
__global__ __launch_bounds__(256, 5) void mlp_scatter(
    const float* __restrict__ leaf, const int* __restrict__ nidx,
    const __bf16* __restrict__ W1T, const __bf16* __restrict__ W2T,
    const float* __restrict__ b1, const float* __restrict__ b2,
    unsigned* __restrict__ agg, int E)
{
    __shared__ __bf16 hs[64][136];      // relu hidden, bf16 (pad 136 -> 2-way max)
    __shared__ int   idx_s[64];
    __shared__ float b1_s[H_DIM], b2_s[H_DIM];

    const int t  = threadIdx.x;
    const int w  = t >> 6;
    const int l  = t & 63;
    const int lr = l & 15;   // row/col within fragment
    const int lg = l >> 4;   // k-group
    const long e0 = (long)blockIdx.x * 64;

    if (t < 64) {
        long e = e0 + t;
        idx_s[t] = nidx[e < E ? e : (E - 1)];
    }
    if (t < H_DIM) { b1_s[t] = b1[t]; b2_s[t] = b2[t]; }

    long erow = e0 + w * 16 + lr;
    if (erow >= E) erow = E - 1;          // clamp (tail-safe; guarded at epilogue)
    const float* arow = leaf + erow * (long)F_IN + lg * 8;
    // B-fragment base for layer 1: W1T[(f*16+lr)][ks*32 + lg*8]
    const __bf16* w1row = W1T + (long)lr * F_IN + lg * 8;

    const v4f vzero = {0.f, 0.f, 0.f, 0.f};
    v4f acc[8];
#pragma unroll
    for (int f = 0; f < 8; ++f) acc[f] = vzero;

    float4 a0 = *(const float4*)(arow);
    float4 a1 = *(const float4*)(arow + 4);

    // ---- layer 1: h = x @ W1, K=384 in 12 steps of 32; W1 frags from L2 ----
    for (int ks = 0; ks < 12; ++ks) {
        float4 n0 = a0, n1 = a1;
        if (ks + 1 < 12) {
            n0 = *(const float4*)(arow + (ks + 1) * 32);
            n1 = *(const float4*)(arow + (ks + 1) * 32 + 4);
        }
        v8bf af;
        af[0] = (__bf16)a0.x; af[1] = (__bf16)a0.y; af[2] = (__bf16)a0.z; af[3] = (__bf16)a0.w;
        af[4] = (__bf16)a1.x; af[5] = (__bf16)a1.y; af[6] = (__bf16)a1.z; af[7] = (__bf16)a1.w;
#pragma unroll
        for (int f = 0; f < 8; ++f) {
            v8bf bfv = *(const v8bf*)(w1row + f * 16 * F_IN + ks * 32);
            acc[f] = __builtin_amdgcn_mfma_f32_16x16x32_bf16(af, bfv, acc[f], 0, 0, 0);
        }
        a0 = n0; a1 = n1;
    }

    __syncthreads();   // b1_s/idx_s staging visible to all

    // ---- relu + bias -> bf16 hidden in LDS ----
#pragma unroll
    for (int f = 0; f < 8; ++f) {
        const float bb = b1_s[f * 16 + lr];
#pragma unroll
        for (int j = 0; j < 4; ++j) {
            float v = acc[f][j] + bb;
            v = fmaxf(v, 0.0f);
            hs[w * 16 + lg * 4 + j][f * 16 + lr] = (__bf16)v;
        }
    }
    __syncthreads();

    // ---- layer 2: m = h @ W2, K=128 in 4 steps; W2T frags from L1/L2 ----
    v4f acc2[8];
#pragma unroll
    for (int f = 0; f < 8; ++f) acc2[f] = vzero;
#pragma unroll
    for (int ks = 0; ks < 4; ++ks) {
        v8bf af2 = *(const v8bf*)&hs[w * 16 + lr][ks * 32 + lg * 8];
#pragma unroll
        for (int f = 0; f < 8; ++f) {
            v8bf bfv = *(const v8bf*)(W2T + (f * 16 + lr) * H_DIM + ks * 32 + lg * 8);
            acc2[f] = __builtin_amdgcn_mfma_f32_16x16x32_bf16(af2, bfv, acc2[f], 0, 0, 0);
        }
    }

    // ---- epilogue: + b2, encode, scatter-max ----
    const int rb = w * 16 + lg * 4;
#pragma unroll
    for (int j = 0; j < 4; ++j) {
        const long ej = e0 + rb + j;
        if (ej < E) {
            const int node = idx_s[rb + j];
            unsigned* dst = agg + (long)node * H_DIM + lr;
#pragma unroll
            for (int f = 0; f < 8; ++f) {
                float v = acc2[f][j] + b2_s[f * 16 + lr];
                atomicMax(dst + f * 16, enc_f32(v));
            }
        }
    }
}

// one wave per node row: lang = center + dec(agg); out = cos(gcn, lang)
__global__ __launch_bounds__(256) void cos_kernel(
    const float* __restrict__ center, const float* __restrict__ gcn,
    const unsigned* __restrict__ agg, float* __restrict__ out, int N)
{
    const int w = threadIdx.x >> 6, l = threadIdx.x & 63;
    const long row = (long)blockIdx.x * 4 + w;
    if (row >= N) return;
    const float2 g2 = *(const float2*)(gcn    + row * H_DIM + l * 2);
    const float2 c2 = *(const float2*)(center + row * H_DIM + l * 2);
    const uint2  e2 = *(const uint2*) (agg    + row * H_DIM + l * 2);
    const float l0 = c2.x + dec_f32(e2.x);
    const float l1 = c2.y + dec_f32(e2.y);
    float sgl = g2.x * l0 + g2.y * l1;
    float sgg = g2.x * g2.x + g2.y * g2.y;
    float sll = l0 * l0 + l1 * l1;
#pragma unroll
    for (int off = 32; off; off >>= 1) {
        sgl += __shfl_xor(sgl, off);
        sgg += __shfl_xor(sgg, off);
        sll += __shfl_xor(sll, off);
    }
    if (l == 0) {
        const float na = fmaxf(sqrtf(sgg), 1e-8f);
        const float nb = fmaxf(sqrtf(sll), 1e-8f);
        out[row] = sgl / (na * nb);
    }
}

extern "C" void kernel_launch(void* const* d_in, const int* in_sizes, int n_in,
                              void* d_out, int out_size, void* d_ws, size_t ws_size,
                              hipStream_t stream) {
    const float* center = (const float*)d_in[0];
    const float* leaf   = (const float*)d_in[1];
    const int*   nidx   = (const int*)  d_in[2];
    const float* gcn    = (const float*)d_in[3];
    const float* W1     = (const float*)d_in[4];
    const float* b1     = (const float*)d_in[5];
    const float* W2     = (const float*)d_in[6];
    const float* b2     = (const float*)d_in[7];

    const int E = in_sizes[2];             // 1,000,000
    const int N = in_sizes[0] / H_DIM;     // 65,536

    unsigned* agg = (unsigned*)d_ws;
    const size_t aggBytes = (size_t)N * H_DIM * sizeof(unsigned);
    __bf16* W1T = (__bf16*)((char*)d_ws + aggBytes);
    __bf16* W2T = W1T + (size_t)F_IN * H_DIM;

    hipMemsetAsync(agg, 0, aggBytes, stream);
    wconvert<<<(F_IN * H_DIM + H_DIM * H_DIM + 255) / 256, 256, 0, stream>>>(W1, W2, W1T, W2T);
    mlp_scatter<<<(E + 63) / 64, 256, 0, stream>>>(leaf, nidx, W1T, W2T, b1, b2, agg, E);
    cos_kernel<<<(N + 3) / 4, 256, 0, stream>>>(center, gcn, agg, (float*)d_out, N);
}

// Round 4
// 801.493 us; speedup vs baseline: 1.7363x; 1.6382x over previous
//
#include <hip/hip_runtime.h>

#define H_DIM 128
#define F_IN  384

typedef __bf16 v8bf __attribute__((ext_vector_type(8)));
typedef float  v4f  __attribute__((ext_vector_type(4)));

// order-preserving float <-> uint encoding for atomicMax
__device__ __forceinline__ unsigned enc_f32(float v) {
    unsigned u = __float_as_uint(v);
    return (u & 0x80000000u) ? ~u : (u | 0x80000000u);
}
__device__ __forceinline__ float dec_f32(unsigned e) {
    if (e == 0u) return 0.0f;  // untouched node -> 0 (matches reference where())
    unsigned u = (e & 0x80000000u) ? (e & 0x7fffffffu) : ~e;
    return __uint_as_float(u);
}

// W1 [F_IN][H] fp32 -> W1T [H][F_IN] bf16 ; W2 [H][H] fp32 -> W2T [H][H] bf16
__global__ __launch_bounds__(256) void wconvert(const float* __restrict__ W1,
                                                const float* __restrict__ W2,
                                                __bf16* __restrict__ W1T,
                                                __bf16* __restrict__ W2T) {
    int i = blockIdx.x * 256 + threadIdx.x;
    if (i < F_IN * H_DIM) {
        int col = i / F_IN, k = i % F_IN;
        W1T[i] = (__bf16)W1[k * H_DIM + col];
    } else if (i < F_IN * H_DIM + H_DIM * H_DIM) {
        int j = i - F_IN * H_DIM;
        int col = j / H_DIM, k = j % H_DIM;
        W2T[j] = (__bf16)W2[k * H_DIM + col];
    }
}

// ---- CSR-ish sort of edges by node: histogram -> scan -> scatter ----
__global__ __launch_bounds__(256) void hist_kernel(const int* __restrict__ nidx,
                                                   int* __restrict__ counts, int E) {
    const int stride = gridDim.x * 256;
    for (int e = blockIdx.x * 256 + threadIdx.x; e < E; e += stride)
        atomicAdd(&counts[nidx[e]], 1);
}

// single block, 1024 threads: exclusive prefix sum of counts[n] -> cursor[n]
__global__ __launch_bounds__(1024) void scan_kernel(const int* __restrict__ counts,
                                                    int* __restrict__ cursor, int n) {
    __shared__ int wsum[16];
    __shared__ int carry;
    const int t = threadIdx.x;
    if (t == 0) carry = 0;
    __syncthreads();
    for (int base = 0; base < n; base += 1024) {
        int v = (base + t < n) ? counts[base + t] : 0;
        int x = v;
#pragma unroll
        for (int off = 1; off < 64; off <<= 1) {
            int y = __shfl_up(x, off);
            if ((t & 63) >= off) x += y;
        }
        if ((t & 63) == 63) wsum[t >> 6] = x;
        __syncthreads();
        if (t < 16) {
            int s = wsum[t];
#pragma unroll
            for (int off = 1; off < 16; off <<= 1) {
                int y = __shfl_up(s, off);
                if (t >= off) s += y;
            }
            wsum[t] = s;
        }
        __syncthreads();
        const int wprev = (t >> 6) ? wsum[(t >> 6) - 1] : 0;
        const int incl = x + wprev + carry;   // inclusive, with carry
        if (base + t < n) cursor[base + t] = incl - v;  // exclusive
        __syncthreads();
        if (t == 1023) carry = incl;
        __syncthreads();
    }
}

__global__ __launch_bounds__(256) void scatter_kernel(const int* __restrict__ nidx,
                                                      int* __restrict__ cursor,
                                                      int* __restrict__ s_eid,
                                                      int* __restrict__ s_nid, int E) {
    const int stride = gridDim.x * 256;
    for (int e = blockIdx.x * 256 + threadIdx.x; e < E; e += stride) {
        const int nd = nidx[e];
        const int p = atomicAdd(&cursor[nd], 1);
        s_eid[p] = e;
        s_nid[p] = nd;
    }
}

// 64 edges/block, 256 threads (4 waves). Round-0 core: double-buffered LDS W1T
// staging + MFMA. New epilogue: block messages -> LDS (overlay), segmented max
// over sorted node runs -> ~1 atomicMax per (node,dim) per block (10x cut).
__global__ __launch_bounds__(256) void mlp_scatter(
    const float* __restrict__ leaf, const int* __restrict__ nidx,
    const int* __restrict__ s_eid, const int* __restrict__ s_nid, int use_sorted,
    const __bf16* __restrict__ W1T, const __bf16* __restrict__ W2T,
    const float* __restrict__ b1, const float* __restrict__ b2,
    unsigned* __restrict__ agg, int E)
{
    // layer phase: wb [2][128][40] bf16 (20480 B) + hs [64][136] bf16 (17408 B)
    // epilogue:    outf [64][132] f32 (33792 B) overlays both (all layer data dead)
    __shared__ char smem_raw[37888] __attribute__((aligned(16)));
    __bf16 (*wb)[128][40] = (__bf16 (*)[128][40])smem_raw;
    __bf16 (*hs)[136]     = (__bf16 (*)[136])(smem_raw + 20480);
    float  (*outf)[132]   = (float (*)[132])smem_raw;
    __shared__ int   idx_s[64];
    __shared__ float b1_s[H_DIM], b2_s[H_DIM];

    const int t  = threadIdx.x;
    const int w  = t >> 6;
    const int l  = t & 63;
    const int lr = l & 15;   // row/col within fragment
    const int lg = l >> 4;   // k-group
    const long e0 = (long)blockIdx.x * 64;

    if (t < 64) {
        const long s = e0 + t;
        idx_s[t] = (s < E) ? (use_sorted ? s_nid[s] : nidx[s]) : -1;
    }
    if (t < H_DIM) { b1_s[t] = b1[t]; b2_s[t] = b2[t]; }

    // stage W1T chunk ks=0 into buffer 0 (each thread: 32B of one column)
    {
        const int col = t >> 1, kh = (t & 1) * 16;
        const v8bf* src = (const v8bf*)(W1T + col * F_IN + kh);
        *(v8bf*)&wb[0][col][kh]     = src[0];
        *(v8bf*)&wb[0][col][kh + 8] = src[1];
    }

    long s = e0 + w * 16 + lr;
    if (s >= E) s = E - 1;                 // clamp (tail-safe; epilogue masks)
    const long erow = use_sorted ? (long)s_eid[s] : s;
    const float* arow = leaf + erow * (long)F_IN + lg * 8;

    const v4f vzero = {0.f, 0.f, 0.f, 0.f};
    v4f acc[8];
#pragma unroll
    for (int f = 0; f < 8; ++f) acc[f] = vzero;

    float4 a0 = *(const float4*)(arow);
    float4 a1 = *(const float4*)(arow + 4);
    __syncthreads();

    // ---- layer 1: h = x @ W1, K=384 in 12 steps of 32 ----
    for (int ks = 0; ks < 12; ++ks) {
        float4 n0 = a0, n1 = a1;
        if (ks + 1 < 12) {
            n0 = *(const float4*)(arow + (ks + 1) * 32);
            n1 = *(const float4*)(arow + (ks + 1) * 32 + 4);
            const int col = t >> 1, kh = (t & 1) * 16;
            const v8bf* src = (const v8bf*)(W1T + col * F_IN + (ks + 1) * 32 + kh);
            const int b = (ks + 1) & 1;
            *(v8bf*)&wb[b][col][kh]     = src[0];
            *(v8bf*)&wb[b][col][kh + 8] = src[1];
        }
        v8bf af;
        af[0] = (__bf16)a0.x; af[1] = (__bf16)a0.y; af[2] = (__bf16)a0.z; af[3] = (__bf16)a0.w;
        af[4] = (__bf16)a1.x; af[5] = (__bf16)a1.y; af[6] = (__bf16)a1.z; af[7] = (__bf16)a1.w;
        const int cb = ks & 1;
#pragma unroll
        for (int f = 0; f < 8; ++f) {
            v8bf bfv = *(const v8bf*)&wb[cb][f * 16 + lr][lg * 8];
            acc[f] = __builtin_amdgcn_mfma_f32_16x16x32_bf16(af, bfv, acc[f], 0, 0, 0);
        }
        a0 = n0; a1 = n1;
        __syncthreads();
    }

    // ---- relu + bias -> bf16 hidden in LDS ----
#pragma unroll
    for (int f = 0; f < 8; ++f) {
        const float bb = b1_s[f * 16 + lr];
#pragma unroll
        for (int j = 0; j < 4; ++j) {
            float v = acc[f][j] + bb;
            v = fmaxf(v, 0.0f);
            hs[w * 16 + lg * 4 + j][f * 16 + lr] = (__bf16)v;
        }
    }
    __syncthreads();

    // ---- layer 2: m = h @ W2, K=128 in 4 steps; W2T frags from L2 ----
    v4f acc2[8];
#pragma unroll
    for (int f = 0; f < 8; ++f) acc2[f] = vzero;
#pragma unroll
    for (int ks = 0; ks < 4; ++ks) {
        v8bf af2 = *(const v8bf*)&hs[w * 16 + lr][ks * 32 + lg * 8];
#pragma unroll
        for (int f = 0; f < 8; ++f) {
            v8bf bfv = *(const v8bf*)(W2T + (f * 16 + lr) * H_DIM + ks * 32 + lg * 8);
            acc2[f] = __builtin_amdgcn_mfma_f32_16x16x32_bf16(af2, bfv, acc2[f], 0, 0, 0);
        }
    }
    __syncthreads();   // all wb/hs reads complete before outf overlay writes

    // ---- epilogue: block messages -> LDS, segmented max over node runs ----
    const int rb = w * 16 + lg * 4;
#pragma unroll
    for (int f = 0; f < 8; ++f) {
        const float bb = b2_s[f * 16 + lr];
#pragma unroll
        for (int j = 0; j < 4; ++j)
            outf[rb + j][f * 16 + lr] = acc2[f][j] + bb;
    }
    __syncthreads();

    // per-column scan: thread t owns dim d over rows half*32..half*32+31;
    // sorted node ids -> long runs -> one atomic per run per dim
    const int d    = t & 127;
    const int half = t >> 7;
    const int r0   = half * 32;
    int   cur = idx_s[r0];
    float run = outf[r0][d];
#pragma unroll 4
    for (int r = r0 + 1; r < r0 + 32; ++r) {
        const int   nd = idx_s[r];
        const float v  = outf[r][d];
        if (nd != cur) {
            if (cur >= 0) atomicMax(agg + (long)cur * H_DIM + d, enc_f32(run));
            cur = nd; run = v;
        } else {
            run = fmaxf(run, v);
        }
    }
    if (cur >= 0) atomicMax(agg + (long)cur * H_DIM + d, enc_f32(run));
}

// one wave per node row: lang = center + dec(agg); out = cos(gcn, lang)
__global__ __launch_bounds__(256) void cos_kernel(
    const float* __restrict__ center, const float* __restrict__ gcn,
    const unsigned* __restrict__ agg, float* __restrict__ out, int N)
{
    const int w = threadIdx.x >> 6, l = threadIdx.x & 63;
    const long row = (long)blockIdx.x * 4 + w;
    if (row >= N) return;
    const float2 g2 = *(const float2*)(gcn    + row * H_DIM + l * 2);
    const float2 c2 = *(const float2*)(center + row * H_DIM + l * 2);
    const uint2  e2 = *(const uint2*) (agg    + row * H_DIM + l * 2);
    const float l0 = c2.x + dec_f32(e2.x);
    const float l1 = c2.y + dec_f32(e2.y);
    float sgl = g2.x * l0 + g2.y * l1;
    float sgg = g2.x * g2.x + g2.y * g2.y;
    float sll = l0 * l0 + l1 * l1;
#pragma unroll
    for (int off = 32; off; off >>= 1) {
        sgl += __shfl_xor(sgl, off);
        sgg += __shfl_xor(sgg, off);
        sll += __shfl_xor(sll, off);
    }
    if (l == 0) {
        const float na = fmaxf(sqrtf(sgg), 1e-8f);
        const float nb = fmaxf(sqrtf(sll), 1e-8f);
        out[row] = sgl / (na * nb);
    }
}

extern "C" void kernel_launch(void* const* d_in, const int* in_sizes, int n_in,
                              void* d_out, int out_size, void* d_ws, size_t ws_size,
                              hipStream_t stream) {
    const float* center = (const float*)d_in[0];
    const float* leaf   = (const float*)d_in[1];
    const int*   nidx   = (const int*)  d_in[2];
    const float* gcn    = (const float*)d_in[3];
    const float* W1     = (const float*)d_in[4];
    const float* b1     = (const float*)d_in[5];
    const float* W2     = (const float*)d_in[6];
    const float* b2     = (const float*)d_in[7];

    const int E = in_sizes[2];             // 1,000,000
    const int N = in_sizes[0] / H_DIM;     // 65,536

    char* ws = (char*)d_ws;
    size_t off = 0;
    unsigned* agg = (unsigned*)(ws + off); off += (size_t)N * H_DIM * sizeof(unsigned);
    __bf16* W1T   = (__bf16*)(ws + off);   off += (size_t)F_IN * H_DIM * sizeof(__bf16);
    __bf16* W2T   = (__bf16*)(ws + off);   off += (size_t)H_DIM * H_DIM * sizeof(__bf16);
    int* counts   = (int*)(ws + off);      off += (size_t)N * sizeof(int);
    int* cursor   = (int*)(ws + off);      off += (size_t)N * sizeof(int);
    int* s_eid    = (int*)(ws + off);      off += (size_t)E * sizeof(int);
    int* s_nid    = (int*)(ws + off);      off += (size_t)E * sizeof(int);
    const int use_sorted = (ws_size >= off) ? 1 : 0;

    hipMemsetAsync(agg, 0, (size_t)N * H_DIM * sizeof(unsigned), stream);
    wconvert<<<(F_IN * H_DIM + H_DIM * H_DIM + 255) / 256, 256, 0, stream>>>(W1, W2, W1T, W2T);
    if (use_sorted) {
        hipMemsetAsync(counts, 0, (size_t)N * sizeof(int), stream);
        hist_kernel<<<2048, 256, 0, stream>>>(nidx, counts, E);
        scan_kernel<<<1, 1024, 0, stream>>>(counts, cursor, N);
        scatter_kernel<<<2048, 256, 0, stream>>>(nidx, cursor, s_eid, s_nid, E);
    }
    mlp_scatter<<<(E + 63) / 64, 256, 0, stream>>>(leaf, nidx, s_eid, s_nid, use_sorted,
                                                   W1T, W2T, b1, b2, agg, E);
    cos_kernel<<<(N + 3) / 4, 256, 0, stream>>>(center, gcn, agg, (float*)d_out, N);
}